// Round 4
// baseline (79.247 us; speedup 1.0000x reference)
//
#include <hip/hip_runtime.h>
#include <math.h>

// Problem constants (B=1)
#define HH   96
#define WW   96
#define NPIX 9216          // H*W = number of pixels = number of gaussians
#define TWT  6             // (96+15)/16
#define THT  6
#define SW   24            // source window per 16x16 tile: rows [r0-3, r0+20]
#define NSRC (SW*SW)       // 576

__device__ __forceinline__ float fast_sigmoid(float x) {
    return 1.0f / (1.0f + __expf(-x));
}
// tanh via exp: exact at saturation, ~1e-7 rel error mid-range.
__device__ __forceinline__ float fast_tanh(float x) {
    return 1.0f - 2.0f / (__expf(2.0f * x) + 1.0f);
}

// Single fused kernel. Each block owns one 16x16 output tile:
//   phase 0: fold head into conv weights (redundant per block, trivial)
//   phase 1: compute gaussian params for the 24x24 source window into LDS
//            (window row-3..row+5 / col-3..col+5 is provably sufficient:
//             |center-pixel| <= 2.04 px for any valid contribution, and
//             center in (src-2, src); +1 px safety margin)
//   phase 2: per-pixel 81-candidate gather from LDS.
// Eliminates the second dispatch (round-3 analysis: dispatch gaps dominate).
__global__ __launch_bounds__(256) void gauss_fused_kernel(
    const float* __restrict__ inp, const float* __restrict__ w_enc,
    const float* __restrict__ b_enc, const float* __restrict__ w_head,
    const float* __restrict__ b_head, float* __restrict__ out)
{
    __shared__ float  wcomb[8][27];  // folded conv weights [o][i*9+ky*3+kx]
    __shared__ float  bcomb[8];
    __shared__ float4 lgA[NSRC];     // (cx, cy, ca, cb)
    __shared__ float4 lgB[NSRC];     // (cc, r, g, b)
    __shared__ int    lgb[NSRC];     // packed tile bounds

    const int tid = threadIdx.x;
    const int bx = blockIdx.x % 6, by = blockIdx.x / 6;
    const int r0 = by * 16, c0 = bx * 16;       // tile origin
    const int sr0 = r0 - 3, sc0 = c0 - 3;       // source window origin

    // ---- phase 0: fold head into conv ----
    if (tid < 216) {
        const int o = tid / 27, r = tid % 27;
        float acc = 0.0f;
        for (int c = 0; c < 64; ++c)
            acc = fmaf(w_head[o * 64 + c], w_enc[c * 27 + r], acc);
        wcomb[o][r] = acc;
    } else if (tid < 224) {
        const int o = tid - 216;
        float acc = b_head[o];
        for (int c = 0; c < 64; ++c)
            acc = fmaf(w_head[o * 64 + c], b_enc[c], acc);
        bcomb[o] = acc;
    }
    __syncthreads();

    // ---- phase 1: params for the 24x24 source window (2.25 rounds) ----
    for (int s = tid; s < NSRC; s += 256) {
        const int sr = s / SW, sc = s - sr * SW;
        const int gr = sr0 + sr, gc = sc0 + sc;   // global source pixel
        if (gr < 0 || gr >= HH || gc < 0 || gc >= WW) continue; // never read back

        // 3x3x3 zero-padded input patch + folded conv
        float pred[8];
        #pragma unroll
        for (int o = 0; o < 8; ++o) pred[o] = bcomb[o];
        #pragma unroll
        for (int i = 0; i < 3; ++i) {
            #pragma unroll
            for (int dy = 0; dy < 3; ++dy) {
                const int y = gr + dy - 1;
                #pragma unroll
                for (int dx = 0; dx < 3; ++dx) {
                    const int x = gc + dx - 1;
                    float v = 0.0f;
                    if (y >= 0 && y < HH && x >= 0 && x < WW)
                        v = inp[i * NPIX + y * WW + x];
                    const int r = (i * 3 + dy) * 3 + dx;
                    #pragma unroll
                    for (int o = 0; o < 8; ++o)
                        pred[o] = fmaf(wcomb[o][r], v, pred[o]);
                }
            }
        }

        // Derived params (reference formulas; theta in [0,2pi] -> hw sin/cos fine)
        const float theta = fast_sigmoid(pred[3]) * 6.28318530717958647692f;
        const float cth = __cosf(theta), sth = __sinf(theta);
        const float s0 = fast_sigmoid(pred[4]) * 0.5f + 1e-6f;
        const float s1 = fast_sigmoid(pred[5]) * 0.5f + 1e-6f;
        const float v0 = s0 * s0, v1 = s1 * s1;
        const float S00 = cth * cth * v0 + sth * sth * v1;
        const float S01 = cth * sth * (v0 - v1);
        const float S11 = sth * sth * v0 + cth * cth * v1;
        const float det = S00 * S11 - S01 * S01;
        const float inv_det = 1.0f / det;
        const float ca = S11 * inv_det;
        const float cb = -S01 * inv_det;
        const float cc = S00 * inv_det;
        const float bmid = 0.5f * (S00 + S11);
        const float lam1 = bmid + sqrtf(fmaxf(0.1f, bmid * bmid - det));
        const float radius = ceilf(3.0f * sqrtf(lam1));   // always 2 or 3
        const float off0 = fast_tanh(pred[6]);
        const float off1 = fast_tanh(pred[7]);
        const float coord0 = 2.0f * (float)gc / (float)WW - 1.0f;
        const float coord1 = 2.0f * (float)gr / (float)HH - 1.0f;
        const float x_ndc = coord0 + 2.0f * off0 / (float)WW - 1.0f / (float)WW;
        const float y_ndc = coord1 + 2.0f * off1 / (float)HH - 1.0f / (float)HH;
        const float cx = 0.5f * (float)WW * (x_ndc + 1.0f) - 0.5f;
        const float cy = 0.5f * (float)HH * (y_ndc + 1.0f) - 0.5f;

        // Tile bounds: trunc-toward-zero cast then clip (matches .astype+clip)
        int tminx = (int)((cx - radius) / 16.0f);
        int tmaxx = (int)((cx + radius) / 16.0f) + 1;
        int tminy = (int)((cy - radius) / 16.0f);
        int tmaxy = (int)((cy + radius) / 16.0f) + 1;
        tminx = min(max(tminx, 0), TWT); tmaxx = min(max(tmaxx, 0), TWT);
        tminy = min(max(tminy, 0), THT); tmaxy = min(max(tmaxy, 0), THT);
        if (!(radius > 0.0f)) { tmaxx = tminx; tmaxy = tminy; }

        lgA[s] = make_float4(cx, cy, ca, cb);
        lgB[s] = make_float4(cc, pred[0], pred[1], pred[2]);
        lgb[s] = tminx | (tmaxx << 8) | (tminy << 16) | (tmaxy << 24);
    }
    __syncthreads();

    // ---- phase 2: rasterize this block's 16x16 tile from LDS ----
    const int lr = tid >> 4, lc = tid & 15;      // local pixel
    const int row = r0 + lr, col = c0 + lc;
    const int tx = col >> 4, ty = row >> 4;
    const float px = (float)col, py = (float)row;

    float aR = 0.0f, aG = 0.0f, aB = 0.0f;
    #pragma unroll
    for (int wr = 0; wr < 9; ++wr) {
        const int gr = row - 3 + wr;
        if (gr < 0 || gr >= HH) continue;
        const int sbase = (lr + wr) * SW + lc;   // source LDS row offset
        for (int wc = 0; wc < 9; ++wc) {
            const int gc = col - 3 + wc;
            if (gc < 0 || gc >= WW) continue;
            const int s = sbase + wc;
            const float4 A  = lgA[s];
            const float4 Bv = lgB[s];
            const float dx = A.x - px;
            const float dy = A.y - py;
            const float sigma = 0.5f * (A.z * dx * dx + Bv.x * dy * dy) + A.w * dx * dy;
            const float alpha = fminf(0.999f, __expf(-sigma));
            const int bnd = lgb[s];
            // NaN sigma -> (sigma>=0) false -> invalid (matches numpy)
            const bool valid = (sigma >= 0.0f) && (alpha >= (1.0f / 255.0f)) &&
                               (tx >= (bnd & 0xff)) && (tx < ((bnd >> 8) & 0xff)) &&
                               (ty >= ((bnd >> 16) & 0xff)) && (ty < ((bnd >> 24) & 0xff));
            if (valid) {
                aR = fmaf(alpha, Bv.y, aR);
                aG = fmaf(alpha, Bv.z, aG);
                aB = fmaf(alpha, Bv.w, aB);
            }
        }
    }
    const int p = row * WW + col;
    out[0 * NPIX + p] = fminf(fmaxf(aR, 0.0f), 1.0f);
    out[1 * NPIX + p] = fminf(fmaxf(aG, 0.0f), 1.0f);
    out[2 * NPIX + p] = fminf(fmaxf(aB, 0.0f), 1.0f);
}

extern "C" void kernel_launch(void* const* d_in, const int* in_sizes, int n_in,
                              void* d_out, int out_size, void* d_ws, size_t ws_size,
                              hipStream_t stream)
{
    const float* inp    = (const float*)d_in[0];  // (1,3,96,96)
    const float* w_enc  = (const float*)d_in[1];  // (64,3,3,3)
    const float* b_enc  = (const float*)d_in[2];  // (64,)
    const float* w_head = (const float*)d_in[3];  // (8,64)
    const float* b_head = (const float*)d_in[4];  // (8,)
    float* out = (float*)d_out;                   // (1,3,96,96)

    gauss_fused_kernel<<<36, 256, 0, stream>>>(inp, w_enc, b_enc, w_head, b_head, out);
}

// Round 5
// 74.074 us; speedup vs baseline: 1.0698x; 1.0698x over previous
//
#include <hip/hip_runtime.h>
#include <math.h>

// Problem constants (B=1)
#define HH   96
#define WW   96
#define NPIX 9216          // H*W = number of pixels = number of gaussians
#define TWT  6             // (96+15)/16
#define THT  6
#define SWC  24            // source-window cols for a 16-wide strip: [c0-3, c0+20]
#define SWR  10            // source-window rows for a 2-row strip:  [r0-3, r0+6]
#define NSRC (SWR*SWC)     // 240

__device__ __forceinline__ float fast_sigmoid(float x) {
    return 1.0f / (1.0f + __expf(-x));
}
// tanh via exp: exact at saturation, ~1e-7 rel error mid-range.
__device__ __forceinline__ float fast_tanh(float x) {
    return 1.0f - 2.0f / (__expf(2.0f * x) + 1.0f);
}

// Single fused kernel, parallelism-preserving (round-4 fusion lost it):
// 288 blocks; each block owns a 2-row x 16-col pixel strip.
//   phase 0: fold head into conv weights (redundant per block, trivial)
//   phase 1: gaussian params for the 10x24 source window into LDS — ONE round
//            (240 <= 256 threads), full occupancy chip-wide (288 blocks).
//   phase 2: 32 pixels x 8 candidate-slices, ~10 LDS evals/lane, 8-lane
//            butterfly reduce. (9x9 window provably sufficient: any valid
//            contribution has |center-pixel| <= 2.04 px, center in (src-2,src);
//            +1 px safety margin.)
__global__ __launch_bounds__(256) void gauss_fused_kernel(
    const float* __restrict__ inp, const float* __restrict__ w_enc,
    const float* __restrict__ b_enc, const float* __restrict__ w_head,
    const float* __restrict__ b_head, float* __restrict__ out)
{
    __shared__ float  wcomb[8][27];  // folded conv weights [o][i*9+ky*3+kx]
    __shared__ float  bcomb[8];
    __shared__ float4 lgA[NSRC];     // (cx, cy, ca, cb)
    __shared__ float4 lgB[NSRC];     // (cc, r, g, b)
    __shared__ int    lgb[NSRC];     // packed tile bounds

    const int tid = threadIdx.x;
    const int bx = blockIdx.x % 6;          // tile column
    const int rp = blockIdx.x / 6;          // row-pair index 0..47
    const int r0 = rp * 2, c0 = bx * 16;    // strip origin
    const int sr0 = r0 - 3, sc0 = c0 - 3;   // source window origin

    // ---- phase 0: fold head into conv ----
    if (tid < 216) {
        const int o = tid / 27, r = tid % 27;
        float acc = 0.0f;
        for (int c = 0; c < 64; ++c)
            acc = fmaf(w_head[o * 64 + c], w_enc[c * 27 + r], acc);
        wcomb[o][r] = acc;
    } else if (tid < 224) {
        const int o = tid - 216;
        float acc = b_head[o];
        for (int c = 0; c < 64; ++c)
            acc = fmaf(w_head[o * 64 + c], b_enc[c], acc);
        bcomb[o] = acc;
    }
    __syncthreads();

    // ---- phase 1: params for the 10x24 source window (one round) ----
    if (tid < NSRC) {
        const int sr = tid / SWC, sc = tid - sr * SWC;
        const int gr = sr0 + sr, gc = sc0 + sc;   // global source pixel
        if (gr >= 0 && gr < HH && gc >= 0 && gc < WW) {
            // 3x3x3 zero-padded input patch + folded conv
            float pred[8];
            #pragma unroll
            for (int o = 0; o < 8; ++o) pred[o] = bcomb[o];
            #pragma unroll
            for (int i = 0; i < 3; ++i) {
                #pragma unroll
                for (int dy = 0; dy < 3; ++dy) {
                    const int y = gr + dy - 1;
                    #pragma unroll
                    for (int dx = 0; dx < 3; ++dx) {
                        const int x = gc + dx - 1;
                        float v = 0.0f;
                        if (y >= 0 && y < HH && x >= 0 && x < WW)
                            v = inp[i * NPIX + y * WW + x];
                        const int r = (i * 3 + dy) * 3 + dx;
                        #pragma unroll
                        for (int o = 0; o < 8; ++o)
                            pred[o] = fmaf(wcomb[o][r], v, pred[o]);
                    }
                }
            }

            // Derived params (reference formulas; theta in [0,2pi] -> hw sin/cos ok)
            const float theta = fast_sigmoid(pred[3]) * 6.28318530717958647692f;
            const float cth = __cosf(theta), sth = __sinf(theta);
            const float s0 = fast_sigmoid(pred[4]) * 0.5f + 1e-6f;
            const float s1 = fast_sigmoid(pred[5]) * 0.5f + 1e-6f;
            const float v0 = s0 * s0, v1 = s1 * s1;
            const float S00 = cth * cth * v0 + sth * sth * v1;
            const float S01 = cth * sth * (v0 - v1);
            const float S11 = sth * sth * v0 + cth * cth * v1;
            const float det = S00 * S11 - S01 * S01;
            const float inv_det = 1.0f / det;
            const float ca = S11 * inv_det;
            const float cb = -S01 * inv_det;
            const float cc = S00 * inv_det;
            const float bmid = 0.5f * (S00 + S11);
            const float lam1 = bmid + sqrtf(fmaxf(0.1f, bmid * bmid - det));
            const float radius = ceilf(3.0f * sqrtf(lam1));   // always 2 or 3
            const float off0 = fast_tanh(pred[6]);
            const float off1 = fast_tanh(pred[7]);
            const float coord0 = 2.0f * (float)gc / (float)WW - 1.0f;
            const float coord1 = 2.0f * (float)gr / (float)HH - 1.0f;
            const float x_ndc = coord0 + 2.0f * off0 / (float)WW - 1.0f / (float)WW;
            const float y_ndc = coord1 + 2.0f * off1 / (float)HH - 1.0f / (float)HH;
            const float cx = 0.5f * (float)WW * (x_ndc + 1.0f) - 0.5f;
            const float cy = 0.5f * (float)HH * (y_ndc + 1.0f) - 0.5f;

            // Tile bounds: trunc-toward-zero cast then clip (matches .astype+clip)
            int tminx = (int)((cx - radius) / 16.0f);
            int tmaxx = (int)((cx + radius) / 16.0f) + 1;
            int tminy = (int)((cy - radius) / 16.0f);
            int tmaxy = (int)((cy + radius) / 16.0f) + 1;
            tminx = min(max(tminx, 0), TWT); tmaxx = min(max(tmaxx, 0), TWT);
            tminy = min(max(tminy, 0), THT); tmaxy = min(max(tmaxy, 0), THT);
            if (!(radius > 0.0f)) { tmaxx = tminx; tmaxy = tminy; }

            lgA[tid] = make_float4(cx, cy, ca, cb);
            lgB[tid] = make_float4(cc, pred[0], pred[1], pred[2]);
            lgb[tid] = tminx | (tmaxx << 8) | (tminy << 16) | (tmaxy << 24);
        }
    }
    __syncthreads();

    // ---- phase 2: 32 pixels x 8 slices, gather from LDS ----
    const int pix   = tid >> 3;          // 0..31 within strip
    const int slice = tid & 7;
    const int lr = pix >> 4, lc = pix & 15;
    const int row = r0 + lr, col = c0 + lc;
    const int tx = col >> 4, ty = row >> 4;
    const float px = (float)col, py = (float)row;

    float aR = 0.0f, aG = 0.0f, aB = 0.0f;
    #pragma unroll
    for (int idx = slice; idx < 81; idx += 8) {
        const int wr = idx / 9, wc = idx - wr * 9;
        const int gr = row - 3 + wr;
        const int gc = col - 3 + wc;
        if (gr < 0 || gr >= HH || gc < 0 || gc >= WW) continue;
        const int s = (lr + wr) * SWC + (lc + wc);
        const float4 A  = lgA[s];
        const float4 Bv = lgB[s];
        const float dx = A.x - px;
        const float dy = A.y - py;
        const float sigma = 0.5f * (A.z * dx * dx + Bv.x * dy * dy) + A.w * dx * dy;
        const float alpha = fminf(0.999f, __expf(-sigma));
        const int bnd = lgb[s];
        // NaN sigma -> (sigma>=0) false -> invalid (matches numpy)
        const bool valid = (sigma >= 0.0f) && (alpha >= (1.0f / 255.0f)) &&
                           (tx >= (bnd & 0xff)) && (tx < ((bnd >> 8) & 0xff)) &&
                           (ty >= ((bnd >> 16) & 0xff)) && (ty < ((bnd >> 24) & 0xff));
        if (valid) {
            aR = fmaf(alpha, Bv.y, aR);
            aG = fmaf(alpha, Bv.z, aG);
            aB = fmaf(alpha, Bv.w, aB);
        }
    }

    // 8-lane butterfly: lanes sharing a pixel are (tid & ~7)..(tid | 7).
    aR += __shfl_xor(aR, 1); aR += __shfl_xor(aR, 2); aR += __shfl_xor(aR, 4);
    aG += __shfl_xor(aG, 1); aG += __shfl_xor(aG, 2); aG += __shfl_xor(aG, 4);
    aB += __shfl_xor(aB, 1); aB += __shfl_xor(aB, 2); aB += __shfl_xor(aB, 4);

    if (slice < 3) {
        const int p = row * WW + col;
        const float v = (slice == 0) ? aR : (slice == 1) ? aG : aB;
        out[slice * NPIX + p] = fminf(fmaxf(v, 0.0f), 1.0f);
    }
}

extern "C" void kernel_launch(void* const* d_in, const int* in_sizes, int n_in,
                              void* d_out, int out_size, void* d_ws, size_t ws_size,
                              hipStream_t stream)
{
    const float* inp    = (const float*)d_in[0];  // (1,3,96,96)
    const float* w_enc  = (const float*)d_in[1];  // (64,3,3,3)
    const float* b_enc  = (const float*)d_in[2];  // (64,)
    const float* w_head = (const float*)d_in[3];  // (8,64)
    const float* b_head = (const float*)d_in[4];  // (8,)
    float* out = (float*)d_out;                   // (1,3,96,96)

    gauss_fused_kernel<<<288, 256, 0, stream>>>(inp, w_enc, b_enc, w_head, b_head, out);
}

// Round 6
// 71.673 us; speedup vs baseline: 1.1057x; 1.0335x over previous
//
#include <hip/hip_runtime.h>
#include <math.h>

// Problem constants (B=1)
#define HH   96
#define WW   96
#define NPIX 9216          // H*W = number of pixels = number of gaussians
#define TWT  6             // (96+15)/16
#define THT  6

__device__ __forceinline__ float fast_sigmoid(float x) {
    return 1.0f / (1.0f + __expf(-x));
}
// tanh via exp: exact at saturation, ~1e-7 rel error mid-range.
__device__ __forceinline__ float fast_tanh(float x) {
    return 1.0f - 2.0f / (__expf(2.0f * x) + 1.0f);
}

// FINAL (round-3 configuration — best measured, 72.8 us):
// Two tiny kernels beat every fusion attempt (rounds 4/5): back-to-back
// dispatch gap < fusion's intra-block barrier + redundancy. The timed window
// is dominated by the harness's 268 MB d_ws poison fill (39.5 us @ 85% HBM
// peak) + dispatch train; kernel compute is ~3 us total.
//
// Workspace layout (AoS float4 pairs so rasterize does 2x dwordx4 + 1 dword per cand):
//   gpA[n] = (cx, cy, ca, cb)
//   gpB[n] = (cc, r, g, b)
//   gb[n]  = packed tile bounds: tminx | tmaxx<<8 | tminy<<16 | tmaxy<<24

// Kernel 1: fused (3x3 conv 3->64) + (1x1 head 64->8) via folded weights,
// then per-gaussian derived parameters.
__global__ __launch_bounds__(256) void gauss_params_kernel(
    const float* __restrict__ inp, const float* __restrict__ w_enc,
    const float* __restrict__ b_enc, const float* __restrict__ w_head,
    const float* __restrict__ b_head,
    float4* __restrict__ gpA, float4* __restrict__ gpB, int* __restrict__ gb)
{
    __shared__ float wcomb[8][27];   // folded conv weights: [o][i*9+ky*3+kx]
    __shared__ float bcomb[8];
    const int tid = threadIdx.x;

    // Fold head into conv weights (redundant per block; trivial).
    if (tid < 216) {
        const int o = tid / 27, r = tid % 27;
        float acc = 0.0f;
        for (int c = 0; c < 64; ++c)
            acc = fmaf(w_head[o * 64 + c], w_enc[c * 27 + r], acc);
        wcomb[o][r] = acc;
    } else if (tid < 224) {
        const int o = tid - 216;
        float acc = b_head[o];
        for (int c = 0; c < 64; ++c)
            acc = fmaf(w_head[o * 64 + c], b_enc[c], acc);
        bcomb[o] = acc;
    }
    __syncthreads();

    const int p   = blockIdx.x * 256 + tid;   // grid is exactly 36 blocks
    const int row = p / WW, col = p % WW;

    // 3x3x3 zero-padded input patch
    float patch[27];
    #pragma unroll
    for (int i = 0; i < 3; ++i) {
        #pragma unroll
        for (int dy = 0; dy < 3; ++dy) {
            const int y = row + dy - 1;
            #pragma unroll
            for (int dx = 0; dx < 3; ++dx) {
                const int x = col + dx - 1;
                float v = 0.0f;
                if (y >= 0 && y < HH && x >= 0 && x < WW)
                    v = inp[i * NPIX + y * WW + x];
                patch[(i * 3 + dy) * 3 + dx] = v;
            }
        }
    }

    float pred[8];
    #pragma unroll
    for (int o = 0; o < 8; ++o) {
        float acc = bcomb[o];
        #pragma unroll
        for (int r = 0; r < 27; ++r)
            acc = fmaf(wcomb[o][r], patch[r], acc);
        pred[o] = acc;
    }

    // Derived gaussian parameters (reference formulas; fast transcendentals —
    // theta in [0,2pi] is inside v_sin/v_cos accurate range).
    const float theta = fast_sigmoid(pred[3]) * 6.28318530717958647692f;
    const float cth = __cosf(theta), sth = __sinf(theta);
    const float s0 = fast_sigmoid(pred[4]) * 0.5f + 1e-6f;
    const float s1 = fast_sigmoid(pred[5]) * 0.5f + 1e-6f;
    const float v0 = s0 * s0, v1 = s1 * s1;
    const float S00 = cth * cth * v0 + sth * sth * v1;
    const float S01 = cth * sth * (v0 - v1);
    const float S11 = sth * sth * v0 + cth * cth * v1;
    const float det = S00 * S11 - S01 * S01;
    const float inv_det = 1.0f / det;
    const float ca = S11 * inv_det;
    const float cb = -S01 * inv_det;
    const float cc = S00 * inv_det;
    const float bmid = 0.5f * (S00 + S11);
    const float lam1 = bmid + sqrtf(fmaxf(0.1f, bmid * bmid - det));
    const float radius = ceilf(3.0f * sqrtf(lam1));   // always 2 or 3 (see analysis)
    const float off0 = fast_tanh(pred[6]);
    const float off1 = fast_tanh(pred[7]);
    const float coord0 = 2.0f * (float)col / (float)WW - 1.0f;
    const float coord1 = 2.0f * (float)row / (float)HH - 1.0f;
    const float x_ndc = coord0 + 2.0f * off0 / (float)WW - 1.0f / (float)WW;
    const float y_ndc = coord1 + 2.0f * off1 / (float)HH - 1.0f / (float)HH;
    const float cx = 0.5f * (float)WW * (x_ndc + 1.0f) - 0.5f;
    const float cy = 0.5f * (float)HH * (y_ndc + 1.0f) - 0.5f;

    // Tile bounds, trunc-toward-zero cast then clip — matches .astype(int32)+clip
    int tminx = (int)((cx - radius) / 16.0f);
    int tmaxx = (int)((cx + radius) / 16.0f) + 1;
    int tminy = (int)((cy - radius) / 16.0f);
    int tmaxy = (int)((cy + radius) / 16.0f) + 1;
    tminx = min(max(tminx, 0), TWT); tmaxx = min(max(tmaxx, 0), TWT);
    tminy = min(max(tminy, 0), THT); tmaxy = min(max(tmaxy, 0), THT);
    if (!(radius > 0.0f)) { tmaxx = tminx; tmaxy = tminy; }  // radius<=0 or NaN -> empty

    gpA[p] = make_float4(cx, cy, ca, cb);
    gpB[p] = make_float4(cc, pred[0], pred[1], pred[2]);
    gb[p]  = tminx | (tmaxx << 8) | (tminy << 16) | (tmaxy << 24);
}

// Kernel 2: per-pixel gather over the provably-sufficient 9x9 source window
// (|center-pixel| <= 2.04 px for any valid contribution, center in (src-2,src);
// +1 px safety margin), split 8 lanes per pixel for TLP, 8-lane butterfly
// reduction. Grid: 288 blocks x 256 = 1152 waves (full chip).
__global__ __launch_bounds__(256) void rasterize_kernel(
    const float4* __restrict__ gpA, const float4* __restrict__ gpB,
    const int* __restrict__ gb, float* __restrict__ out)
{
    const int t     = blockIdx.x * 256 + threadIdx.x;
    const int p     = t >> 3;        // pixel index
    const int slice = t & 7;         // candidate slice within the 9x9 window
    const int row = p / WW, col = p % WW;
    const int tx = col >> 4, ty = row >> 4;
    const float px = (float)col, py = (float)row;

    float aR = 0.0f, aG = 0.0f, aB = 0.0f;
    for (int idx = slice; idx < 81; idx += 8) {
        const int wr = idx / 9, wc = idx - wr * 9;
        const int gr = row - 3 + wr;
        const int gc = col - 3 + wc;
        if (gr < 0 || gr >= HH || gc < 0 || gc >= WW) continue;
        const int n = gr * WW + gc;
        const float4 A  = gpA[n];
        const float4 Bv = gpB[n];
        const float dx = A.x - px;
        const float dy = A.y - py;
        const float sigma = 0.5f * (A.z * dx * dx + Bv.x * dy * dy) + A.w * dx * dy;
        const float alpha = fminf(0.999f, __expf(-sigma));
        const int bnd = gb[n];
        // NaN sigma -> (sigma>=0) false -> invalid (matches numpy semantics)
        const bool valid = (sigma >= 0.0f) && (alpha >= (1.0f / 255.0f)) &&
                           (tx >= (bnd & 0xff)) && (tx < ((bnd >> 8) & 0xff)) &&
                           (ty >= ((bnd >> 16) & 0xff)) && (ty < ((bnd >> 24) & 0xff));
        if (valid) {
            aR = fmaf(alpha, Bv.y, aR);
            aG = fmaf(alpha, Bv.z, aG);
            aB = fmaf(alpha, Bv.w, aB);
        }
    }

    // 8-lane butterfly: lanes (t & ~7)..(t|7) share a pixel; masks 1/2/4 stay inside.
    aR += __shfl_xor(aR, 1); aR += __shfl_xor(aR, 2); aR += __shfl_xor(aR, 4);
    aG += __shfl_xor(aG, 1); aG += __shfl_xor(aG, 2); aG += __shfl_xor(aG, 4);
    aB += __shfl_xor(aB, 1); aB += __shfl_xor(aB, 2); aB += __shfl_xor(aB, 4);

    if (slice < 3) {
        const float v = (slice == 0) ? aR : (slice == 1) ? aG : aB;
        out[slice * NPIX + p] = fminf(fmaxf(v, 0.0f), 1.0f);
    }
}

extern "C" void kernel_launch(void* const* d_in, const int* in_sizes, int n_in,
                              void* d_out, int out_size, void* d_ws, size_t ws_size,
                              hipStream_t stream)
{
    const float* inp    = (const float*)d_in[0];  // (1,3,96,96)
    const float* w_enc  = (const float*)d_in[1];  // (64,3,3,3)
    const float* b_enc  = (const float*)d_in[2];  // (64,)
    const float* w_head = (const float*)d_in[3];  // (8,64)
    const float* b_head = (const float*)d_in[4];  // (8,)
    float* out = (float*)d_out;                   // (1,3,96,96)

    float4* gpA = (float4*)d_ws;                  // NPIX float4
    float4* gpB = gpA + NPIX;                     // NPIX float4
    int*    gb  = (int*)(gpB + NPIX);             // NPIX ints  (total ~332 KB)

    gauss_params_kernel<<<36, 256, 0, stream>>>(inp, w_enc, b_enc, w_head, b_head, gpA, gpB, gb);
    rasterize_kernel<<<(NPIX * 8) / 256, 256, 0, stream>>>(gpA, gpB, gb, out);
}